// Round 11
// baseline (153.276 us; speedup 1.0000x reference)
//
#include <hip/hip_runtime.h>
#include <math.h>

#define BB 8
#define DD 192
#define LLD 128
#define LLP 1024
#define FC1 1024
#define FC2 1024
#define FC3 512
#define NCLS 2
#define LT 16   // l-tile for tiled GEMM kernels

// ---------------------------------------------------------------------------
// Fused projections: y[b*L+l, e] = sum_d x[b,d,l]*W[e,d] + bias[e]  (f32)
// blocks 0..63 = drug (L=128), 64..575 = protein (L=1024). 192 threads.
// Register-blocked r=4: thread = (et, lg); owns e=4*et..+3, l=l0+4*lg..+3.
// ---------------------------------------------------------------------------
__global__ void proj_both_kernel(const float* __restrict__ drug,
                                 const float* __restrict__ prot,
                                 const float* __restrict__ Wd,
                                 const float* __restrict__ bdv,
                                 const float* __restrict__ Wp,
                                 const float* __restrict__ bpv,
                                 float* __restrict__ d_att,
                                 float* __restrict__ p_att) {
    int blk = blockIdx.x;
    const float *x, *W, *bias;
    float* y;
    int L, b, l0;
    if (blk < BB * (LLD / LT)) {            // 64 drug tiles
        x = drug; W = Wd; bias = bdv; y = d_att; L = LLD;
        b = blk >> 3; l0 = (blk & 7) * LT;
    } else {                                 // 512 protein tiles
        int idx = blk - BB * (LLD / LT);
        x = prot; W = Wp; bias = bpv; y = p_att; L = LLP;
        b = idx >> 6; l0 = (idx & 63) * LT;
    }
    int tid = threadIdx.x;  // 0..191

    __shared__ float xs[LT][DD + 4];   // row stride 196 floats (16B-aligned)

    const float* xbase = x + (size_t)b * DD * L + l0;
#pragma unroll
    for (int k = 0; k < LT; ++k) {
        int idx = tid + k * DD;        // covers DD*LT = 3072
        int d = idx >> 4;
        int j = idx & (LT - 1);
        xs[j][d] = xbase[(size_t)d * L + j];
    }
    __syncthreads();

    int et = tid % 48;
    int lg = tid / 48;       // 0..3
    int e0 = et * 4;
    int jl0 = lg * 4;

    float acc[4][4];         // [e][l]
#pragma unroll
    for (int i = 0; i < 4; ++i) {
        float be = bias[e0 + i];
#pragma unroll
        for (int j = 0; j < 4; ++j) acc[i][j] = be;
    }

    const float4* W4 = (const float4*)W;   // row e = 48 float4
#pragma unroll 2
    for (int d4 = 0; d4 < DD / 4; ++d4) {
        float4 h[4];
#pragma unroll
        for (int j = 0; j < 4; ++j)
            h[j] = *(const float4*)&xs[jl0 + j][d4 * 4];
#pragma unroll
        for (int i = 0; i < 4; ++i) {
            float4 w = W4[(size_t)(e0 + i) * (DD / 4) + d4];
#pragma unroll
            for (int j = 0; j < 4; ++j) {
                acc[i][j] = fmaf(h[j].x, w.x, acc[i][j]);
                acc[i][j] = fmaf(h[j].y, w.y, acc[i][j]);
                acc[i][j] = fmaf(h[j].z, w.z, acc[i][j]);
                acc[i][j] = fmaf(h[j].w, w.w, acc[i][j]);
            }
        }
    }

    float* ybase = y + ((size_t)b * L + l0) * DD;
#pragma unroll
    for (int j = 0; j < 4; ++j) {
        float4 v = make_float4(acc[0][j], acc[1][j], acc[2][j], acc[3][j]);
        *(float4*)&ybase[(size_t)(jl0 + j) * DD + e0] = v;
    }
}

// ---------------------------------------------------------------------------
// Sort+prefix cross pass. One block per (b, d-pair): 768 blocks, 256 thr.
// Parallel 7-step scans for suffix sums and histogram prefix.
// ---------------------------------------------------------------------------
__global__ void cross_sort_kernel(const float* __restrict__ da,
                                  const float* __restrict__ pa,
                                  float* __restrict__ Hd_t,
                                  float* __restrict__ Hp_t) {
    int blk = blockIdx.x;            // 0..767
    int b = blk / (DD / 2);
    int dp = blk - b * (DD / 2);
    int d0 = dp * 2;
    int tid = threadIdx.x;           // 0..255

    __shared__ float skey[2][LLD];
    __shared__ int   sidx[2][LLD];
    __shared__ float sufs[2][LLD + 1];
    __shared__ int   cnt[2][LLD + 1];
    __shared__ float val[2][LLD + 1];

    // load keys + init perm
    {
        int a = tid >> 7, l = tid & 127;
        skey[a][l] = da[((size_t)b * LLD + l) * DD + d0 + a];
        sidx[a][l] = l;
    }
    // zero histograms (2 * 129 entries) + suffix tail
    for (int i = tid; i < 2 * (LLD + 1); i += 256) {
        int a = i / (LLD + 1), k = i - a * (LLD + 1);
        cnt[a][k] = 0;
        val[a][k] = 0.f;
    }
    if (tid < 2) sufs[tid][LLD] = 0.f;
    __syncthreads();

    // bitonic ascending sort of both 128-element arrays
    {
        int a = tid >> 7, i = tid & 127;
        for (int k = 2; k <= LLD; k <<= 1) {
            for (int j = k >> 1; j > 0; j >>= 1) {
                int ixj = i ^ j;
                if (ixj > i) {
                    float ki = skey[a][i], kj = skey[a][ixj];
                    bool up = ((i & k) == 0);
                    if ((ki > kj) == up) {
                        skey[a][i] = kj; skey[a][ixj] = ki;
                        int t = sidx[a][i]; sidx[a][i] = sidx[a][ixj]; sidx[a][ixj] = t;
                    }
                }
                __syncthreads();
            }
        }
    }

    // parallel suffix sums: sufs[i] = sum_{r>=i} skey[r]  (Hillis-Steele)
    {
        int a = tid >> 7, i = tid & 127;
        sufs[a][i] = skey[a][i];
        __syncthreads();
        for (int off = 1; off < LLD; off <<= 1) {
            float v = (i + off < LLD) ? sufs[a][i + off] : 0.f;
            __syncthreads();
            sufs[a][i] += v;
            __syncthreads();
        }
    }

    // queries: 8 batches of (128 p x 2 d)
    {
        int d_i = tid & 1, prow = tid >> 1;
        float* hprow = Hp_t + ((size_t)b * DD + d0 + d_i) * LLP;
        const float* qbase = pa + (size_t)b * LLP * DD + d0 + d_i;
#pragma unroll
        for (int batch = 0; batch < LLP / 128; ++batch) {
            int p = batch * 128 + prow;
            float q = qbase[(size_t)p * DD];
            float nq = -q;
            int pos = 0;
#pragma unroll
            for (int st = LLD; st > 0; st >>= 1) {
                int np = pos + st;
                if (np <= LLD && skey[d_i][np - 1] <= nq) pos = np;
            }
            hprow[p] = ((float)(LLD - pos) * q + sufs[d_i][pos]) * (1.0f / LLD);
            atomicAdd(&cnt[d_i][pos], 1);
            atomicAdd(&val[d_i][pos], q);
        }
    }
    __syncthreads();

    // parallel inclusive prefix over bins 0..127 (bin 128 never used)
    {
        int a = tid >> 7, i = tid & 127;
        for (int off = 1; off < LLD; off <<= 1) {
            int c = 0; float v = 0.f;
            if (i >= off) { c = cnt[a][i - off]; v = val[a][i - off]; }
            __syncthreads();
            cnt[a][i] += c;
            val[a][i] += v;
            __syncthreads();
        }
    }

    // finalize Hd: rank r of array a -> original row sidx[a][r]
    {
        int a = tid >> 7, r = tid & 127;
        float hv = (skey[a][r] * (float)cnt[a][r] + val[a][r]) * (1.0f / LLP);
        Hd_t[((size_t)b * DD + d0 + a) * LLD + sidx[a][r]] = hv;
    }
}

// ---------------------------------------------------------------------------
// Sigmoid-GEMM for both sides, reading transposed H (B,D,L), writing
// transposed gate (B,D,L). Register-blocked r=4 like proj. 192 threads.
// ---------------------------------------------------------------------------
__global__ void gemm_sig_both_kernel(const float* __restrict__ Hd_t,
                                     const float* __restrict__ Hp_t,
                                     const float* __restrict__ Wa,
                                     const float* __restrict__ ba,
                                     float* __restrict__ catt_t,
                                     float* __restrict__ psig_t) {
    int blk = blockIdx.x;
    const float* Ht;
    float* out_t;
    int L, b, l0;
    if (blk < BB * (LLD / LT)) {
        b = blk >> 3; l0 = (blk & 7) * LT;
        Ht = Hd_t; out_t = catt_t; L = LLD;
    } else {
        int idx = blk - BB * (LLD / LT);
        b = idx >> 6; l0 = (idx & 63) * LT;
        Ht = Hp_t; out_t = psig_t; L = LLP;
    }
    int tid = threadIdx.x;

    __shared__ float hs[LT][DD + 4];
    __shared__ float cs[LT][DD + 1];

    // each thread owns d-row `tid`: 16 consecutive floats (one 64B line)
    const float* hrow = Ht + ((size_t)b * DD + tid) * L + l0;
#pragma unroll
    for (int j = 0; j < LT; ++j) hs[j][tid] = hrow[j];
    __syncthreads();

    int et = tid % 48;
    int lg = tid / 48;
    int e0 = et * 4;
    int jl0 = lg * 4;

    float acc[4][4];
#pragma unroll
    for (int i = 0; i < 4; ++i) {
        float be = ba[e0 + i];
#pragma unroll
        for (int j = 0; j < 4; ++j) acc[i][j] = be;
    }

    const float4* W4 = (const float4*)Wa;
#pragma unroll 2
    for (int d4 = 0; d4 < DD / 4; ++d4) {
        float4 h[4];
#pragma unroll
        for (int j = 0; j < 4; ++j)
            h[j] = *(const float4*)&hs[jl0 + j][d4 * 4];
#pragma unroll
        for (int i = 0; i < 4; ++i) {
            float4 w = W4[(size_t)(e0 + i) * (DD / 4) + d4];
#pragma unroll
            for (int j = 0; j < 4; ++j) {
                acc[i][j] = fmaf(h[j].x, w.x, acc[i][j]);
                acc[i][j] = fmaf(h[j].y, w.y, acc[i][j]);
                acc[i][j] = fmaf(h[j].z, w.z, acc[i][j]);
                acc[i][j] = fmaf(h[j].w, w.w, acc[i][j]);
            }
        }
    }

#pragma unroll
    for (int i = 0; i < 4; ++i)
#pragma unroll
        for (int j = 0; j < 4; ++j)
            cs[jl0 + j][e0 + i] = 1.0f / (1.0f + __expf(-acc[i][j]));
    __syncthreads();

    float* obase = out_t + (size_t)b * DD * L + l0;
    for (int k = tid; k < LT * DD; k += DD) {
        int eo = k >> 4;
        int j = k & (LT - 1);
        obase[(size_t)eo * L + j] = cs[j][eo];
    }
}

// ---------------------------------------------------------------------------
// One wave per (b,d). Coalesced contiguous reads; shfl butterfly max-reduce.
// ---------------------------------------------------------------------------
__global__ void pool_pair_kernel(const float* __restrict__ drug,
                                 const float* __restrict__ prot,
                                 const float* __restrict__ catt_t,
                                 const float* __restrict__ psig_t,
                                 float* __restrict__ pair) {
    int bd = blockIdx.x;           // b*DD + d
    int b = bd / DD;
    int d = bd - b * DD;
    int lane = threadIdx.x;        // 0..63

    const float* dr = drug + (size_t)bd * LLD;
    const float* ca = catt_t + (size_t)bd * LLD;
    float m1 = -INFINITY;
#pragma unroll
    for (int k = 0; k < LLD / 64; ++k) {
        int l = lane + 64 * k;
        m1 = fmaxf(m1, dr[l] * (0.5f + ca[l]));
    }

    const float* pr = prot + (size_t)bd * LLP;
    const float* ps = psig_t + (size_t)bd * LLP;
    float m2 = -INFINITY;
#pragma unroll
    for (int k = 0; k < LLP / 64; ++k) {
        int p = lane + 64 * k;
        m2 = fmaxf(m2, pr[p] * (0.5f + ps[p]));
    }

#pragma unroll
    for (int off = 32; off > 0; off >>= 1) {
        m1 = fmaxf(m1, __shfl_xor(m1, off));
        m2 = fmaxf(m2, __shfl_xor(m2, off));
    }
    if (lane == 0) {
        pair[b * 2 * DD + d] = m1;
        pair[b * 2 * DD + DD + d] = m2;
    }
}

// One 64-lane wave per output (b,j). float4 lanes split K (coalesced).
__global__ void fc_wave_kernel(const float* __restrict__ x,
                               const float* __restrict__ W,
                               const float* __restrict__ bias,
                               float* __restrict__ y,
                               int K, int N, int leaky) {
    int gtid = blockIdx.x * blockDim.x + threadIdx.x;
    int wid = gtid >> 6;
    int lane = gtid & 63;
    if (wid >= BB * N) return;
    int b = wid / N;
    int j = wid - b * N;
    const float4* xr = (const float4*)(x + (size_t)b * K);
    const float4* Wr = (const float4*)(W + (size_t)j * K);
    int K4 = K >> 2;
    float s = 0.f;
    for (int k = lane; k < K4; k += 64) {
        float4 xv = xr[k];
        float4 wv = Wr[k];
        s = fmaf(xv.x, wv.x, s);
        s = fmaf(xv.y, wv.y, s);
        s = fmaf(xv.z, wv.z, s);
        s = fmaf(xv.w, wv.w, s);
    }
#pragma unroll
    for (int off = 32; off > 0; off >>= 1) s += __shfl_xor(s, off);
    if (lane == 0) {
        float acc = s + bias[j];
        if (leaky) acc = (acc > 0.f) ? acc : 0.01f * acc;
        y[wid] = acc;
    }
}

extern "C" void kernel_launch(void* const* d_in, const int* in_sizes, int n_in,
                              void* d_out, int out_size, void* d_ws, size_t ws_size,
                              hipStream_t stream) {
    const float* drug = (const float*)d_in[0];   // (B,D,LD)
    const float* prot = (const float*)d_in[1];   // (B,D,LP)
    const float* Wd = (const float*)d_in[2];
    const float* bd = (const float*)d_in[3];
    const float* Wp = (const float*)d_in[4];
    const float* bp = (const float*)d_in[5];
    const float* Wa = (const float*)d_in[6];
    const float* ba = (const float*)d_in[7];
    const float* W1 = (const float*)d_in[8];
    const float* b1 = (const float*)d_in[9];
    const float* W2 = (const float*)d_in[10];
    const float* b2 = (const float*)d_in[11];
    const float* W3 = (const float*)d_in[12];
    const float* b3 = (const float*)d_in[13];
    const float* Wo = (const float*)d_in[14];
    const float* bo = (const float*)d_in[15];
    float* out = (float*)d_out;

    float* ws = (float*)d_ws;
    const size_t n_datt = (size_t)BB * LLD * DD;   // 196608
    const size_t n_patt = (size_t)BB * LLP * DD;   // 1572864
    float* d_att  = ws;                     // (B*LD, D)
    float* p_att  = d_att + n_datt;         // (B*LP, D)
    float* Hd_t   = p_att + n_patt;         // (B,D,LD)
    float* Hp_t   = Hd_t + n_datt;          // (B,D,LP)
    float* catt_t = Hp_t + n_patt;          // (B,D,LD)
    float* psig_t = catt_t + n_datt;        // (B,D,LP)
    float* pair   = psig_t + n_patt;        // B*2D
    float* h1     = pair + (size_t)BB * 2 * DD;
    float* h2     = h1 + (size_t)BB * FC1;
    float* h3     = h2 + (size_t)BB * FC2;
    // total ~5.3M floats (~21 MB)

    // 1) both projections, one launch (register-blocked)
    proj_both_kernel<<<BB * (LLD / LT) + BB * (LLP / LT), DD, 0, stream>>>(
        drug, prot, Wd, bd, Wp, bp, d_att, p_att);

    // 2) sort+prefix cross pass (exact f32), parallel scans
    cross_sort_kernel<<<BB * (DD / 2), 256, 0, stream>>>(d_att, p_att, Hd_t, Hp_t);

    // 3) both sigmoid-GEMMs (register-blocked), transposed gates
    gemm_sig_both_kernel<<<BB * (LLD / LT) + BB * (LLP / LT), DD, 0, stream>>>(
        Hd_t, Hp_t, Wa, ba, catt_t, psig_t);

    // 4) gated residual + maxpool -> pair (B, 2D); wave per (b,d)
    pool_pair_kernel<<<BB * DD, 64, 0, stream>>>(drug, prot, catt_t, psig_t, pair);

    // 5) MLP — wave per output element
    fc_wave_kernel<<<(BB * FC1 * 64) / 256, 256, 0, stream>>>(pair, W1, b1, h1, 2 * DD, FC1, 1);
    fc_wave_kernel<<<(BB * FC2 * 64) / 256, 256, 0, stream>>>(h1, W2, b2, h2, FC1, FC2, 1);
    fc_wave_kernel<<<(BB * FC3 * 64) / 256, 256, 0, stream>>>(h2, W3, b3, h3, FC2, FC3, 1);
    fc_wave_kernel<<<(BB * NCLS * 64 + 255) / 256, 256, 0, stream>>>(h3, Wo, bo, out, FC3, NCLS, 0);
}

// Round 12
// 99.491 us; speedup vs baseline: 1.5406x; 1.5406x over previous
//
#include <hip/hip_runtime.h>
#include <math.h>

#define BB 8
#define DD 192
#define LLD 128
#define LLP 1024
#define FC1 1024
#define FC2 1024
#define FC3 512
#define NCLS 2
#define LT 8   // l-tile for tiled GEMM kernels (8 -> 1152 blocks, 4.5/CU)

// ---------------------------------------------------------------------------
// Fused projections: y[b*L+l, e] = sum_d x[b,d,l]*W[e,d] + bias[e]  (f32)
// blocks 0..127 = drug (L=128), 128..1151 = protein (L=1024). 192 threads.
// Thread = output channel e; xs reads are LDS broadcasts; W row walk is
// sequential per thread (L1-friendly).
// ---------------------------------------------------------------------------
__global__ void proj_both_kernel(const float* __restrict__ drug,
                                 const float* __restrict__ prot,
                                 const float* __restrict__ Wd,
                                 const float* __restrict__ bdv,
                                 const float* __restrict__ Wp,
                                 const float* __restrict__ bpv,
                                 float* __restrict__ d_att,
                                 float* __restrict__ p_att) {
    int blk = blockIdx.x;
    const float *x, *W, *bias;
    float* y;
    int L, b, l0;
    if (blk < BB * (LLD / LT)) {            // 128 drug tiles
        x = drug; W = Wd; bias = bdv; y = d_att; L = LLD;
        b = blk >> 4; l0 = (blk & 15) * LT;
    } else {                                 // 1024 protein tiles
        int idx = blk - BB * (LLD / LT);
        x = prot; W = Wp; bias = bpv; y = p_att; L = LLP;
        b = idx >> 7; l0 = (idx & 127) * LT;
    }
    int tid = threadIdx.x;  // 0..191

    __shared__ float xs[LT][DD + 4];

    const float* xbase = x + (size_t)b * DD * L + l0;
#pragma unroll
    for (int k = 0; k < LT; ++k) {
        int idx = tid + k * DD;        // covers DD*LT = 1536
        int d = idx >> 3;
        int j = idx & (LT - 1);
        xs[j][d] = xbase[(size_t)d * L + j];
    }
    __syncthreads();

    const int e = tid;
    const float be = bias[e];
    float acc[LT];
#pragma unroll
    for (int j = 0; j < LT; ++j) acc[j] = be;

    const float4* Wr4 = (const float4*)(W + (size_t)e * DD);
#pragma unroll 2
    for (int d4 = 0; d4 < DD / 4; ++d4) {
        float4 w = Wr4[d4];
#pragma unroll
        for (int j = 0; j < LT; ++j) {
            float4 h = *(const float4*)&xs[j][d4 * 4];   // broadcast
            acc[j] = fmaf(h.x, w.x, acc[j]);
            acc[j] = fmaf(h.y, w.y, acc[j]);
            acc[j] = fmaf(h.z, w.z, acc[j]);
            acc[j] = fmaf(h.w, w.w, acc[j]);
        }
    }

    float* ybase = y + ((size_t)b * L + l0) * DD;
#pragma unroll
    for (int j = 0; j < LT; ++j)
        ybase[(size_t)j * DD + e] = acc[j];
}

// ---------------------------------------------------------------------------
// Sort+prefix cross pass. One block per (b, d-pair): 768 blocks, 256 thr.
// Parallel 7-step scans for suffix sums and histogram prefix.
// ---------------------------------------------------------------------------
__global__ void cross_sort_kernel(const float* __restrict__ da,
                                  const float* __restrict__ pa,
                                  float* __restrict__ Hd_t,
                                  float* __restrict__ Hp_t) {
    int blk = blockIdx.x;            // 0..767
    int b = blk / (DD / 2);
    int dp = blk - b * (DD / 2);
    int d0 = dp * 2;
    int tid = threadIdx.x;           // 0..255

    __shared__ float skey[2][LLD];
    __shared__ int   sidx[2][LLD];
    __shared__ float sufs[2][LLD + 1];
    __shared__ int   cnt[2][LLD + 1];
    __shared__ float val[2][LLD + 1];

    // load keys + init perm
    {
        int a = tid >> 7, l = tid & 127;
        skey[a][l] = da[((size_t)b * LLD + l) * DD + d0 + a];
        sidx[a][l] = l;
    }
    // zero histograms (2 * 129 entries) + suffix tail
    for (int i = tid; i < 2 * (LLD + 1); i += 256) {
        int a = i / (LLD + 1), k = i - a * (LLD + 1);
        cnt[a][k] = 0;
        val[a][k] = 0.f;
    }
    if (tid < 2) sufs[tid][LLD] = 0.f;
    __syncthreads();

    // bitonic ascending sort of both 128-element arrays
    {
        int a = tid >> 7, i = tid & 127;
        for (int k = 2; k <= LLD; k <<= 1) {
            for (int j = k >> 1; j > 0; j >>= 1) {
                int ixj = i ^ j;
                if (ixj > i) {
                    float ki = skey[a][i], kj = skey[a][ixj];
                    bool up = ((i & k) == 0);
                    if ((ki > kj) == up) {
                        skey[a][i] = kj; skey[a][ixj] = ki;
                        int t = sidx[a][i]; sidx[a][i] = sidx[a][ixj]; sidx[a][ixj] = t;
                    }
                }
                __syncthreads();
            }
        }
    }

    // parallel suffix sums: sufs[i] = sum_{r>=i} skey[r]  (Hillis-Steele)
    {
        int a = tid >> 7, i = tid & 127;
        sufs[a][i] = skey[a][i];
        __syncthreads();
        for (int off = 1; off < LLD; off <<= 1) {
            float v = (i + off < LLD) ? sufs[a][i + off] : 0.f;
            __syncthreads();
            sufs[a][i] += v;
            __syncthreads();
        }
    }

    // queries: 8 batches of (128 p x 2 d)
    {
        int d_i = tid & 1, prow = tid >> 1;
        float* hprow = Hp_t + ((size_t)b * DD + d0 + d_i) * LLP;
        const float* qbase = pa + (size_t)b * LLP * DD + d0 + d_i;
#pragma unroll
        for (int batch = 0; batch < LLP / 128; ++batch) {
            int p = batch * 128 + prow;
            float q = qbase[(size_t)p * DD];
            float nq = -q;
            int pos = 0;
#pragma unroll
            for (int st = LLD; st > 0; st >>= 1) {
                int np = pos + st;
                if (np <= LLD && skey[d_i][np - 1] <= nq) pos = np;
            }
            hprow[p] = ((float)(LLD - pos) * q + sufs[d_i][pos]) * (1.0f / LLD);
            atomicAdd(&cnt[d_i][pos], 1);
            atomicAdd(&val[d_i][pos], q);
        }
    }
    __syncthreads();

    // parallel inclusive prefix over bins 0..127 (bin 128 never used)
    {
        int a = tid >> 7, i = tid & 127;
        for (int off = 1; off < LLD; off <<= 1) {
            int c = 0; float v = 0.f;
            if (i >= off) { c = cnt[a][i - off]; v = val[a][i - off]; }
            __syncthreads();
            cnt[a][i] += c;
            val[a][i] += v;
            __syncthreads();
        }
    }

    // finalize Hd: rank r of array a -> original row sidx[a][r]
    {
        int a = tid >> 7, r = tid & 127;
        float hv = (skey[a][r] * (float)cnt[a][r] + val[a][r]) * (1.0f / LLP);
        Hd_t[((size_t)b * DD + d0 + a) * LLD + sidx[a][r]] = hv;
    }
}

// ---------------------------------------------------------------------------
// Sigmoid-GEMM for both sides, reading transposed H (B,D,L), writing
// transposed gate (B,D,L). Thread = e; hs reads are broadcasts. 192 threads.
// blocks 0..127 drug, 128..1151 protein.
// ---------------------------------------------------------------------------
__global__ void gemm_sig_both_kernel(const float* __restrict__ Hd_t,
                                     const float* __restrict__ Hp_t,
                                     const float* __restrict__ Wa,
                                     const float* __restrict__ ba,
                                     float* __restrict__ catt_t,
                                     float* __restrict__ psig_t) {
    int blk = blockIdx.x;
    const float* Ht;
    float* out_t;
    int L, b, l0;
    if (blk < BB * (LLD / LT)) {
        b = blk >> 4; l0 = (blk & 15) * LT;
        Ht = Hd_t; out_t = catt_t; L = LLD;
    } else {
        int idx = blk - BB * (LLD / LT);
        b = idx >> 7; l0 = (idx & 127) * LT;
        Ht = Hp_t; out_t = psig_t; L = LLP;
    }
    int tid = threadIdx.x;

    __shared__ float hs[LT][DD + 4];
    __shared__ float cs[LT][DD + 1];

    // each thread owns d-row `tid`: LT consecutive floats
    const float* hrow = Ht + ((size_t)b * DD + tid) * L + l0;
#pragma unroll
    for (int j = 0; j < LT; ++j) hs[j][tid] = hrow[j];
    __syncthreads();

    const int e = tid;
    const float bias = ba[e];
    float acc[LT];
#pragma unroll
    for (int j = 0; j < LT; ++j) acc[j] = bias;

    const float4* Wr4 = (const float4*)(Wa + (size_t)e * DD);
#pragma unroll 2
    for (int d4 = 0; d4 < DD / 4; ++d4) {
        float4 w = Wr4[d4];
#pragma unroll
        for (int j = 0; j < LT; ++j) {
            float4 h = *(const float4*)&hs[j][d4 * 4];   // broadcast
            acc[j] = fmaf(h.x, w.x, acc[j]);
            acc[j] = fmaf(h.y, w.y, acc[j]);
            acc[j] = fmaf(h.z, w.z, acc[j]);
            acc[j] = fmaf(h.w, w.w, acc[j]);
        }
    }

#pragma unroll
    for (int j = 0; j < LT; ++j)
        cs[j][e] = 1.0f / (1.0f + __expf(-acc[j]));
    __syncthreads();

    float* obase = out_t + (size_t)b * DD * L + l0;
    for (int k = tid; k < LT * DD; k += DD) {
        int eo = k >> 3;
        int j = k & (LT - 1);
        obase[(size_t)eo * L + j] = cs[j][eo];
    }
}

// ---------------------------------------------------------------------------
// One wave per (b,d). Coalesced contiguous reads; shfl butterfly max-reduce.
// ---------------------------------------------------------------------------
__global__ void pool_pair_kernel(const float* __restrict__ drug,
                                 const float* __restrict__ prot,
                                 const float* __restrict__ catt_t,
                                 const float* __restrict__ psig_t,
                                 float* __restrict__ pair) {
    int bd = blockIdx.x;           // b*DD + d
    int b = bd / DD;
    int d = bd - b * DD;
    int lane = threadIdx.x;        // 0..63

    const float* dr = drug + (size_t)bd * LLD;
    const float* ca = catt_t + (size_t)bd * LLD;
    float m1 = -INFINITY;
#pragma unroll
    for (int k = 0; k < LLD / 64; ++k) {
        int l = lane + 64 * k;
        m1 = fmaxf(m1, dr[l] * (0.5f + ca[l]));
    }

    const float* pr = prot + (size_t)bd * LLP;
    const float* ps = psig_t + (size_t)bd * LLP;
    float m2 = -INFINITY;
#pragma unroll
    for (int k = 0; k < LLP / 64; ++k) {
        int p = lane + 64 * k;
        m2 = fmaxf(m2, pr[p] * (0.5f + ps[p]));
    }

#pragma unroll
    for (int off = 32; off > 0; off >>= 1) {
        m1 = fmaxf(m1, __shfl_xor(m1, off));
        m2 = fmaxf(m2, __shfl_xor(m2, off));
    }
    if (lane == 0) {
        pair[b * 2 * DD + d] = m1;
        pair[b * 2 * DD + DD + d] = m2;
    }
}

// One 64-lane wave per output (b,j). float4 lanes split K (coalesced).
__global__ void fc_wave_kernel(const float* __restrict__ x,
                               const float* __restrict__ W,
                               const float* __restrict__ bias,
                               float* __restrict__ y,
                               int K, int N, int leaky) {
    int gtid = blockIdx.x * blockDim.x + threadIdx.x;
    int wid = gtid >> 6;
    int lane = gtid & 63;
    if (wid >= BB * N) return;
    int b = wid / N;
    int j = wid - b * N;
    const float4* xr = (const float4*)(x + (size_t)b * K);
    const float4* Wr = (const float4*)(W + (size_t)j * K);
    int K4 = K >> 2;
    float s = 0.f;
    for (int k = lane; k < K4; k += 64) {
        float4 xv = xr[k];
        float4 wv = Wr[k];
        s = fmaf(xv.x, wv.x, s);
        s = fmaf(xv.y, wv.y, s);
        s = fmaf(xv.z, wv.z, s);
        s = fmaf(xv.w, wv.w, s);
    }
#pragma unroll
    for (int off = 32; off > 0; off >>= 1) s += __shfl_xor(s, off);
    if (lane == 0) {
        float acc = s + bias[j];
        if (leaky) acc = (acc > 0.f) ? acc : 0.01f * acc;
        y[wid] = acc;
    }
}

extern "C" void kernel_launch(void* const* d_in, const int* in_sizes, int n_in,
                              void* d_out, int out_size, void* d_ws, size_t ws_size,
                              hipStream_t stream) {
    const float* drug = (const float*)d_in[0];   // (B,D,LD)
    const float* prot = (const float*)d_in[1];   // (B,D,LP)
    const float* Wd = (const float*)d_in[2];
    const float* bd = (const float*)d_in[3];
    const float* Wp = (const float*)d_in[4];
    const float* bp = (const float*)d_in[5];
    const float* Wa = (const float*)d_in[6];
    const float* ba = (const float*)d_in[7];
    const float* W1 = (const float*)d_in[8];
    const float* b1 = (const float*)d_in[9];
    const float* W2 = (const float*)d_in[10];
    const float* b2 = (const float*)d_in[11];
    const float* W3 = (const float*)d_in[12];
    const float* b3 = (const float*)d_in[13];
    const float* Wo = (const float*)d_in[14];
    const float* bo = (const float*)d_in[15];
    float* out = (float*)d_out;

    float* ws = (float*)d_ws;
    const size_t n_datt = (size_t)BB * LLD * DD;   // 196608
    const size_t n_patt = (size_t)BB * LLP * DD;   // 1572864
    float* d_att  = ws;                     // (B*LD, D)
    float* p_att  = d_att + n_datt;         // (B*LP, D)
    float* Hd_t   = p_att + n_patt;         // (B,D,LD)
    float* Hp_t   = Hd_t + n_datt;          // (B,D,LP)
    float* catt_t = Hp_t + n_patt;          // (B,D,LD)
    float* psig_t = catt_t + n_datt;        // (B,D,LP)
    float* pair   = psig_t + n_patt;        // B*2D
    float* h1     = pair + (size_t)BB * 2 * DD;
    float* h2     = h1 + (size_t)BB * FC1;
    float* h3     = h2 + (size_t)BB * FC2;
    // total ~5.3M floats (~21 MB)

    // 1) both projections, one launch (thread-per-e, LT=8)
    proj_both_kernel<<<BB * (LLD / LT) + BB * (LLP / LT), DD, 0, stream>>>(
        drug, prot, Wd, bd, Wp, bp, d_att, p_att);

    // 2) sort+prefix cross pass (exact f32), parallel scans
    cross_sort_kernel<<<BB * (DD / 2), 256, 0, stream>>>(d_att, p_att, Hd_t, Hp_t);

    // 3) both sigmoid-GEMMs (thread-per-e, LT=8), transposed gates
    gemm_sig_both_kernel<<<BB * (LLD / LT) + BB * (LLP / LT), DD, 0, stream>>>(
        Hd_t, Hp_t, Wa, ba, catt_t, psig_t);

    // 4) gated residual + maxpool -> pair (B, 2D); wave per (b,d)
    pool_pair_kernel<<<BB * DD, 64, 0, stream>>>(drug, prot, catt_t, psig_t, pair);

    // 5) MLP — wave per output element
    fc_wave_kernel<<<(BB * FC1 * 64) / 256, 256, 0, stream>>>(pair, W1, b1, h1, 2 * DD, FC1, 1);
    fc_wave_kernel<<<(BB * FC2 * 64) / 256, 256, 0, stream>>>(h1, W2, b2, h2, FC1, FC2, 1);
    fc_wave_kernel<<<(BB * FC3 * 64) / 256, 256, 0, stream>>>(h2, W3, b3, h3, FC2, FC3, 1);
    fc_wave_kernel<<<(BB * NCLS * 64 + 255) / 256, 256, 0, stream>>>(h3, Wo, bo, out, FC3, NCLS, 0);
}

// Round 13
// 94.236 us; speedup vs baseline: 1.6265x; 1.0558x over previous
//
#include <hip/hip_runtime.h>
#include <math.h>

#define BB 8
#define DD 192
#define LLD 128
#define LLP 1024
#define FC1 1024
#define FC2 1024
#define FC3 512
#define NCLS 2
#define LT 8   // l-tile for tiled GEMM kernels

__device__ __forceinline__ void atomicMaxFloat(float* addr, float value) {
    if (value >= 0.f)
        atomicMax((int*)addr, __float_as_int(value));
    else
        atomicMin((unsigned int*)addr, __float_as_uint(value));
}

// ---------------------------------------------------------------------------
// Fused projections: y[b*L+l, e] = sum_d x[b,d,l]*W[e,d] + bias[e]  (f32)
// blocks 0..127 = drug (L=128), 128..1151 = protein (L=1024). 192 threads.
// ---------------------------------------------------------------------------
__global__ void proj_both_kernel(const float* __restrict__ drug,
                                 const float* __restrict__ prot,
                                 const float* __restrict__ Wd,
                                 const float* __restrict__ bdv,
                                 const float* __restrict__ Wp,
                                 const float* __restrict__ bpv,
                                 float* __restrict__ d_att,
                                 float* __restrict__ p_att) {
    int blk = blockIdx.x;
    const float *x, *W, *bias;
    float* y;
    int L, b, l0;
    if (blk < BB * (LLD / LT)) {            // 128 drug tiles
        x = drug; W = Wd; bias = bdv; y = d_att; L = LLD;
        b = blk >> 4; l0 = (blk & 15) * LT;
    } else {                                 // 1024 protein tiles
        int idx = blk - BB * (LLD / LT);
        x = prot; W = Wp; bias = bpv; y = p_att; L = LLP;
        b = idx >> 7; l0 = (idx & 127) * LT;
    }
    int tid = threadIdx.x;  // 0..191

    __shared__ float xs[LT][DD + 4];

    const float* xbase = x + (size_t)b * DD * L + l0;
#pragma unroll
    for (int k = 0; k < LT; ++k) {
        int idx = tid + k * DD;        // covers DD*LT = 1536
        int d = idx >> 3;
        int j = idx & (LT - 1);
        xs[j][d] = xbase[(size_t)d * L + j];
    }
    __syncthreads();

    const int e = tid;
    const float be = bias[e];
    float acc[LT];
#pragma unroll
    for (int j = 0; j < LT; ++j) acc[j] = be;

    const float4* Wr4 = (const float4*)(W + (size_t)e * DD);
#pragma unroll 2
    for (int d4 = 0; d4 < DD / 4; ++d4) {
        float4 w = Wr4[d4];
#pragma unroll
        for (int j = 0; j < LT; ++j) {
            float4 h = *(const float4*)&xs[j][d4 * 4];   // broadcast
            acc[j] = fmaf(h.x, w.x, acc[j]);
            acc[j] = fmaf(h.y, w.y, acc[j]);
            acc[j] = fmaf(h.z, w.z, acc[j]);
            acc[j] = fmaf(h.w, w.w, acc[j]);
        }
    }

    float* ybase = y + ((size_t)b * L + l0) * DD;
#pragma unroll
    for (int j = 0; j < LT; ++j)
        ybase[(size_t)j * DD + e] = acc[j];
}

// ---------------------------------------------------------------------------
// Sort+prefix cross pass. One block per (b, d-pair): 768 blocks, 256 thr.
// Also initializes pair[] to -inf for the fused gemm+pool that follows.
// ---------------------------------------------------------------------------
__global__ void cross_sort_kernel(const float* __restrict__ da,
                                  const float* __restrict__ pa,
                                  float* __restrict__ Hd_t,
                                  float* __restrict__ Hp_t,
                                  float* __restrict__ pair) {
    int blk = blockIdx.x;            // 0..767
    int b = blk / (DD / 2);
    int dp = blk - b * (DD / 2);
    int d0 = dp * 2;
    int tid = threadIdx.x;           // 0..255

    __shared__ float skey[2][LLD];
    __shared__ int   sidx[2][LLD];
    __shared__ float sufs[2][LLD + 1];
    __shared__ int   cnt[2][LLD + 1];
    __shared__ float val[2][LLD + 1];

    // init pair entries owned by this block (consumed by next kernel)
    if (tid < 4) {
        int side = tid >> 1;
        int dd = d0 + (tid & 1);
        pair[b * 2 * DD + side * DD + dd] = -INFINITY;
    }

    // load keys + init perm
    {
        int a = tid >> 7, l = tid & 127;
        skey[a][l] = da[((size_t)b * LLD + l) * DD + d0 + a];
        sidx[a][l] = l;
    }
    // zero histograms (2 * 129 entries) + suffix tail
    for (int i = tid; i < 2 * (LLD + 1); i += 256) {
        int a = i / (LLD + 1), k = i - a * (LLD + 1);
        cnt[a][k] = 0;
        val[a][k] = 0.f;
    }
    if (tid < 2) sufs[tid][LLD] = 0.f;
    __syncthreads();

    // bitonic ascending sort of both 128-element arrays
    {
        int a = tid >> 7, i = tid & 127;
        for (int k = 2; k <= LLD; k <<= 1) {
            for (int j = k >> 1; j > 0; j >>= 1) {
                int ixj = i ^ j;
                if (ixj > i) {
                    float ki = skey[a][i], kj = skey[a][ixj];
                    bool up = ((i & k) == 0);
                    if ((ki > kj) == up) {
                        skey[a][i] = kj; skey[a][ixj] = ki;
                        int t = sidx[a][i]; sidx[a][i] = sidx[a][ixj]; sidx[a][ixj] = t;
                    }
                }
                __syncthreads();
            }
        }
    }

    // parallel suffix sums: sufs[i] = sum_{r>=i} skey[r]  (Hillis-Steele)
    {
        int a = tid >> 7, i = tid & 127;
        sufs[a][i] = skey[a][i];
        __syncthreads();
        for (int off = 1; off < LLD; off <<= 1) {
            float v = (i + off < LLD) ? sufs[a][i + off] : 0.f;
            __syncthreads();
            sufs[a][i] += v;
            __syncthreads();
        }
    }

    // queries: 8 batches of (128 p x 2 d)
    {
        int d_i = tid & 1, prow = tid >> 1;
        float* hprow = Hp_t + ((size_t)b * DD + d0 + d_i) * LLP;
        const float* qbase = pa + (size_t)b * LLP * DD + d0 + d_i;
#pragma unroll
        for (int batch = 0; batch < LLP / 128; ++batch) {
            int p = batch * 128 + prow;
            float q = qbase[(size_t)p * DD];
            float nq = -q;
            int pos = 0;
#pragma unroll
            for (int st = LLD; st > 0; st >>= 1) {
                int np = pos + st;
                if (np <= LLD && skey[d_i][np - 1] <= nq) pos = np;
            }
            hprow[p] = ((float)(LLD - pos) * q + sufs[d_i][pos]) * (1.0f / LLD);
            atomicAdd(&cnt[d_i][pos], 1);
            atomicAdd(&val[d_i][pos], q);
        }
    }
    __syncthreads();

    // parallel inclusive prefix over bins 0..127 (bin 128 never used)
    {
        int a = tid >> 7, i = tid & 127;
        for (int off = 1; off < LLD; off <<= 1) {
            int c = 0; float v = 0.f;
            if (i >= off) { c = cnt[a][i - off]; v = val[a][i - off]; }
            __syncthreads();
            cnt[a][i] += c;
            val[a][i] += v;
            __syncthreads();
        }
    }

    // finalize Hd: rank r of array a -> original row sidx[a][r]
    {
        int a = tid >> 7, r = tid & 127;
        float hv = (skey[a][r] * (float)cnt[a][r] + val[a][r]) * (1.0f / LLP);
        Hd_t[((size_t)b * DD + d0 + a) * LLD + sidx[a][r]] = hv;
    }
}

// ---------------------------------------------------------------------------
// Fused sigmoid-GEMM + gated max-pool. Thread = e. No gate materialization:
// gate stays in registers, multiplied by x[b,e,l0+j], max-reduced, one
// atomicMax per (block, thread) into pair.
// blocks 0..127 drug -> pair[b, e]; 128..1151 protein -> pair[b, D+e].
// ---------------------------------------------------------------------------
__global__ void gemm_sig_pool_kernel(const float* __restrict__ Hd_t,
                                     const float* __restrict__ Hp_t,
                                     const float* __restrict__ Wa,
                                     const float* __restrict__ ba,
                                     const float* __restrict__ drug,
                                     const float* __restrict__ prot,
                                     float* __restrict__ pair) {
    int blk = blockIdx.x;
    const float* Ht;
    const float* xsrc;
    int L, b, l0, side;
    if (blk < BB * (LLD / LT)) {
        b = blk >> 4; l0 = (blk & 15) * LT;
        Ht = Hd_t; xsrc = drug; L = LLD; side = 0;
    } else {
        int idx = blk - BB * (LLD / LT);
        b = idx >> 7; l0 = (idx & 127) * LT;
        Ht = Hp_t; xsrc = prot; L = LLP; side = 1;
    }
    int tid = threadIdx.x;

    __shared__ float hs[LT][DD + 4];

    // each thread owns d-row `tid`: LT consecutive floats
    const float* hrow = Ht + ((size_t)b * DD + tid) * L + l0;
#pragma unroll
    for (int j = 0; j < LT; ++j) hs[j][tid] = hrow[j];
    __syncthreads();

    const int e = tid;
    const float bias = ba[e];
    float acc[LT];
#pragma unroll
    for (int j = 0; j < LT; ++j) acc[j] = bias;

    const float4* Wr4 = (const float4*)(Wa + (size_t)e * DD);
#pragma unroll 2
    for (int d4 = 0; d4 < DD / 4; ++d4) {
        float4 w = Wr4[d4];
#pragma unroll
        for (int j = 0; j < LT; ++j) {
            float4 h = *(const float4*)&hs[j][d4 * 4];   // broadcast
            acc[j] = fmaf(h.x, w.x, acc[j]);
            acc[j] = fmaf(h.y, w.y, acc[j]);
            acc[j] = fmaf(h.z, w.z, acc[j]);
            acc[j] = fmaf(h.w, w.w, acc[j]);
        }
    }

    // gated max-pool epilogue (gate in registers, x row = 8 contiguous floats)
    const float* xrow = xsrc + ((size_t)b * DD + e) * L + l0;
    float4 x0 = *(const float4*)&xrow[0];
    float4 x1 = *(const float4*)&xrow[4];
    float xv[LT] = {x0.x, x0.y, x0.z, x0.w, x1.x, x1.y, x1.z, x1.w};
    float m = -INFINITY;
#pragma unroll
    for (int j = 0; j < LT; ++j) {
        float gate = 0.5f + 1.0f / (1.0f + __expf(-acc[j]));
        m = fmaxf(m, xv[j] * gate);
    }
    atomicMaxFloat(&pair[b * 2 * DD + side * DD + e], m);
}

// One 64-lane wave per output (b,j). float4 lanes split K (coalesced).
__global__ void fc_wave_kernel(const float* __restrict__ x,
                               const float* __restrict__ W,
                               const float* __restrict__ bias,
                               float* __restrict__ y,
                               int K, int N, int leaky) {
    int gtid = blockIdx.x * blockDim.x + threadIdx.x;
    int wid = gtid >> 6;
    int lane = gtid & 63;
    if (wid >= BB * N) return;
    int b = wid / N;
    int j = wid - b * N;
    const float4* xr = (const float4*)(x + (size_t)b * K);
    const float4* Wr = (const float4*)(W + (size_t)j * K);
    int K4 = K >> 2;
    float s = 0.f;
    for (int k = lane; k < K4; k += 64) {
        float4 xv = xr[k];
        float4 wv = Wr[k];
        s = fmaf(xv.x, wv.x, s);
        s = fmaf(xv.y, wv.y, s);
        s = fmaf(xv.z, wv.z, s);
        s = fmaf(xv.w, wv.w, s);
    }
#pragma unroll
    for (int off = 32; off > 0; off >>= 1) s += __shfl_xor(s, off);
    if (lane == 0) {
        float acc = s + bias[j];
        if (leaky) acc = (acc > 0.f) ? acc : 0.01f * acc;
        y[wid] = acc;
    }
}

extern "C" void kernel_launch(void* const* d_in, const int* in_sizes, int n_in,
                              void* d_out, int out_size, void* d_ws, size_t ws_size,
                              hipStream_t stream) {
    const float* drug = (const float*)d_in[0];   // (B,D,LD)
    const float* prot = (const float*)d_in[1];   // (B,D,LP)
    const float* Wd = (const float*)d_in[2];
    const float* bd = (const float*)d_in[3];
    const float* Wp = (const float*)d_in[4];
    const float* bp = (const float*)d_in[5];
    const float* Wa = (const float*)d_in[6];
    const float* ba = (const float*)d_in[7];
    const float* W1 = (const float*)d_in[8];
    const float* b1 = (const float*)d_in[9];
    const float* W2 = (const float*)d_in[10];
    const float* b2 = (const float*)d_in[11];
    const float* W3 = (const float*)d_in[12];
    const float* b3 = (const float*)d_in[13];
    const float* Wo = (const float*)d_in[14];
    const float* bo = (const float*)d_in[15];
    float* out = (float*)d_out;

    float* ws = (float*)d_ws;
    const size_t n_datt = (size_t)BB * LLD * DD;   // 196608
    const size_t n_patt = (size_t)BB * LLP * DD;   // 1572864
    float* d_att  = ws;                     // (B*LD, D)
    float* p_att  = d_att + n_datt;         // (B*LP, D)
    float* Hd_t   = p_att + n_patt;         // (B,D,LD)
    float* Hp_t   = Hd_t + n_datt;          // (B,D,LP)
    float* pair   = Hp_t + n_patt;          // B*2D
    float* h1     = pair + (size_t)BB * 2 * DD;
    float* h2     = h1 + (size_t)BB * FC1;
    float* h3     = h2 + (size_t)BB * FC2;
    // total ~3.6M floats (~14 MB)

    // 1) both projections, one launch (thread-per-e, LT=8)
    proj_both_kernel<<<BB * (LLD / LT) + BB * (LLP / LT), DD, 0, stream>>>(
        drug, prot, Wd, bd, Wp, bp, d_att, p_att);

    // 2) sort+prefix cross pass (exact f32) + pair init
    cross_sort_kernel<<<BB * (DD / 2), 256, 0, stream>>>(d_att, p_att, Hd_t, Hp_t, pair);

    // 3) fused sigmoid-GEMM + gated max-pool -> pair
    gemm_sig_pool_kernel<<<BB * (LLD / LT) + BB * (LLP / LT), DD, 0, stream>>>(
        Hd_t, Hp_t, Wa, ba, drug, prot, pair);

    // 4) MLP — wave per output element
    fc_wave_kernel<<<(BB * FC1 * 64) / 256, 256, 0, stream>>>(pair, W1, b1, h1, 2 * DD, FC1, 1);
    fc_wave_kernel<<<(BB * FC2 * 64) / 256, 256, 0, stream>>>(h1, W2, b2, h2, FC1, FC2, 1);
    fc_wave_kernel<<<(BB * FC3 * 64) / 256, 256, 0, stream>>>(h2, W3, b3, h3, FC2, FC3, 1);
    fc_wave_kernel<<<(BB * NCLS * 64 + 255) / 256, 256, 0, stream>>>(h3, Wo, bo, out, FC3, NCLS, 0);
}